// Round 17
// baseline (519.376 us; speedup 1.0000x reference)
//
#include <hip/hip_runtime.h>

typedef unsigned short u16;
typedef short s8v __attribute__((ext_vector_type(8)));
typedef float f4v __attribute__((ext_vector_type(4)));

#define SEQ 1025
#define BATCH 8
#define MROWS (BATCH * SEQ)   // 8200
#define D 512
#define TD 1536
#define F 352
#define F2I 768               // interleaved+padded w1/w3 rows
#define FPAD 384
#define NLAYERS 6
#define QKVS ((size_t)BATCH * 8 * SEQ * 64)   // elements per Q/K/V transposed slab set
#define EPS 132               // padded fp32 epilogue stride (128-wide tiles)
#define EPS64 68              // padded fp32 epilogue stride (64-wide tiles)

__device__ __forceinline__ u16 f2b(float f) {
    unsigned u;
    __builtin_memcpy(&u, &f, 4);
    unsigned r = u + 0x7fffu + ((u >> 16) & 1u);
    return (u16)(r >> 16);
}
__device__ __forceinline__ float b2f(u16 h) {
    unsigned u = ((unsigned)h) << 16;
    float f;
    __builtin_memcpy(&f, &u, 4);
    return f;
}
__device__ __forceinline__ float rs_of(float ssq) {
    return rsqrtf(ssq * (1.0f / (float)D) + 1e-5f);
}

// ---------------- fused weight conversion + ssq zeroing + init (one launch) ----------------
#define SEG0 (NLAYERS * TD * (D / 4))            // 1179648 (multiple of 256)
#define SEG1 (SEG0 + NLAYERS * D * (D / 4))      // +393216
#define SEG2 (SEG1 + NLAYERS * F2I * (D / 4))    // +589824
#define SEG3 (SEG2 + NLAYERS * D * (FPAD / 4))   // +294912
#define SEG4P (SEG3 + ((12 * MROWS / 4 + 255) & ~255))   // ssq zero, padded to 256
#define SEG5 (SEG4P + MROWS * 128)               // init: 128 threads/row
__global__ __launch_bounds__(256) void convAll_k(const float* __restrict__ wqkv, const float* __restrict__ anw,
                                                 const float* __restrict__ wo,
                                                 const float* __restrict__ w1, const float* __restrict__ w3,
                                                 const float* __restrict__ fnw,
                                                 const float* __restrict__ w2,
                                                 u16* __restrict__ wqkvb, u16* __restrict__ wob,
                                                 u16* __restrict__ w13b, u16* __restrict__ w2b,
                                                 float* __restrict__ ssqz,
                                                 const float* __restrict__ xin, float* __restrict__ x,
                                                 u16* __restrict__ xb, float* __restrict__ ssq0) {
    int i = blockIdx.x * 256 + threadIdx.x;
    if (i < SEG0) {
        int k4 = i & 127;
        int rem = i >> 7;
        int l = rem / TD;
        float4 v = ((const float4*)wqkv)[i];
        float4 w = ((const float4*)(anw + (size_t)l * D))[k4];
        ushort4 r;
        r.x = f2b(v.x * w.x); r.y = f2b(v.y * w.y); r.z = f2b(v.z * w.z); r.w = f2b(v.w * w.w);
        ((ushort4*)wqkvb)[i] = r;
    } else if (i < SEG1) {
        int j = i - SEG0;
        float4 v = ((const float4*)wo)[j];
        ushort4 r;
        r.x = f2b(v.x); r.y = f2b(v.y); r.z = f2b(v.z); r.w = f2b(v.w);
        ((ushort4*)wob)[j] = r;
    } else if (i < SEG2) {
        int j = i - SEG1;
        int k4 = j & 127;
        int rem = j >> 7;                            // l*768 + n
        int n = rem % F2I, l = rem / F2I;
        int k32 = n >> 5, jj = n & 31;
        int f = k32 * 16 + (jj & 15);
        ushort4 r;
        if (f < F) {
            const float* src = (jj < 16) ? (w1 + ((size_t)(l * F + f) * D))
                                         : (w3 + ((size_t)(l * F + f) * D));
            float4 v = ((const float4*)src)[k4];
            float4 w = ((const float4*)(fnw + (size_t)l * D))[k4];
            r.x = f2b(v.x * w.x); r.y = f2b(v.y * w.y); r.z = f2b(v.z * w.z); r.w = f2b(v.w * w.w);
        } else {
            r.x = 0; r.y = 0; r.z = 0; r.w = 0;
        }
        ((ushort4*)w13b)[j] = r;
    } else if (i < SEG3) {
        int j = i - SEG2;
        int k4 = j % (FPAD / 4);
        int rem = j / (FPAD / 4);
        int n = rem % D, l = rem / D;
        ushort4 r;
        if (k4 < F / 4) {
            float4 v = ((const float4*)(w2 + (size_t)(l * D + n) * F))[k4];
            r.x = f2b(v.x); r.y = f2b(v.y); r.z = f2b(v.z); r.w = f2b(v.w);
        } else {
            r.x = 0; r.y = 0; r.z = 0; r.w = 0;
        }
        ((ushort4*)w2b)[j] = r;
    } else if (i < SEG4P) {
        int j = i - SEG3;
        if (j < 12 * MROWS / 4) {
            float4 z = {0.f, 0.f, 0.f, 0.f};
            ((float4*)ssqz)[j] = z;
        }
    } else if (i < SEG5) {
        int j = i - SEG4P;
        int row = j >> 7, t = j & 127;
        int tid = threadIdx.x;
        float4 v = ((const float4*)(xin + (size_t)row * D))[t];
        ((float4*)(x + (size_t)row * D))[t] = v;
        ushort4 pk;
        pk.x = f2b(v.x); pk.y = f2b(v.y); pk.z = f2b(v.z); pk.w = f2b(v.w);
        ((ushort4*)(xb + (size_t)row * D))[t] = pk;
        float ss = v.x * v.x + v.y * v.y + v.z * v.z + v.w * v.w;
        #pragma unroll
        for (int off = 32; off; off >>= 1) ss += __shfl_xor(ss, off);
        __shared__ float red[4];
        if ((tid & 63) == 0) red[tid >> 6] = ss;
        __syncthreads();
        if (tid == 0) ssq0[row] = red[0] + red[1];
        if (tid == 128) ssq0[row] = red[2] + red[3];
    }
}

// ---------------- GEMM 128x128 (MODE 2: QKV scatter), 780 blocks, 64KB dbuf (2/CU) ----------------
#define STAGE_GEMM(bufofs, kk)                                                          \
    do {                                                                                \
        int k0_ = (kk);                                                                 \
        _Pragma("unroll")                                                               \
        for (int i_ = 0; i_ < 4; ++i_) {                                                \
            int chunk_ = i_ * 256 + tid;                                                \
            int row_ = chunk_ >> 3, kc_ = chunk_ & 7;                                   \
            int gr_ = tm + row_;                                                        \
            gr_ = gr_ < MROWS ? gr_ : MROWS - 1;                                        \
            const u16* srcA_ = A + (size_t)gr_ * K + k0_ + ((kc_ ^ (row_ & 7)) << 3);   \
            __builtin_amdgcn_global_load_lds(                                           \
                (const __attribute__((address_space(1))) void*)srcA_,                   \
                (__attribute__((address_space(3))) void*)(smem + (bufofs) + (size_t)chunk_ * 8), \
                16, 0, 0);                                                              \
            const u16* srcB_ = B + (size_t)(tn + row_) * K + k0_ + ((kc_ ^ (row_ & 7)) << 3); \
            __builtin_amdgcn_global_load_lds(                                           \
                (const __attribute__((address_space(1))) void*)srcB_,                   \
                (__attribute__((address_space(3))) void*)(smem + 16384 + (bufofs) + (size_t)chunk_ * 8), \
                16, 0, 0);                                                              \
        }                                                                               \
    } while (0)

template <int K, int NX, int NWG>
__global__ __launch_bounds__(256) void gemm_qkv_k(const u16* __restrict__ A, const u16* __restrict__ B,
                                                  void* __restrict__ C, const float* __restrict__ ssqIn) {
    __shared__ u16 smem[34048];
    const int tid = threadIdx.x;
    const int lane = tid & 63;
    const int wave = tid >> 6;
    int hw = blockIdx.x;
    constexpr int q8 = NWG >> 3, r8 = NWG & 7;
    int xcd = hw & 7, pos = hw >> 3;
    int work = (xcd < r8 ? xcd * (q8 + 1) : r8 * (q8 + 1) + (xcd - r8) * q8) + pos;
    int ty = work / NX, tx = work - ty * NX;
    const int tm = ty * 128;
    const int tn = tx * 128;
    const int wm = (wave >> 1) * 64;
    const int wn = (wave & 1) * 64;
    f4v acc[4][4] = {};

    constexpr int nk = K >> 6;
    STAGE_GEMM(0, 0);
    __syncthreads();
    #pragma unroll
    for (int k = 0; k < nk; ++k) {
        int cur = (k & 1) * 8192;
        if (k + 1 < nk) STAGE_GEMM(cur ^ 8192, (k + 1) << 6);
        const u16* sa_ = smem + cur;
        const u16* sb_ = smem + 16384 + cur;
        #pragma unroll
        for (int ks = 0; ks < 2; ++ks) {
            int kc = ks * 4 + (lane >> 4);
            s8v af[4], bfr[4];
            #pragma unroll
            for (int mi = 0; mi < 4; ++mi) {
                int row = wm + mi * 16 + (lane & 15);
                af[mi] = *(const s8v*)(sa_ + row * 64 + ((kc ^ (row & 7)) << 3));
            }
            #pragma unroll
            for (int ni = 0; ni < 4; ++ni) {
                int row = wn + ni * 16 + (lane & 15);
                bfr[ni] = *(const s8v*)(sb_ + row * 64 + ((kc ^ (row & 7)) << 3));
            }
            #pragma unroll
            for (int mi = 0; mi < 4; ++mi)
                #pragma unroll
                for (int ni = 0; ni < 4; ++ni)
                    acc[mi][ni] = __builtin_amdgcn_mfma_f32_16x16x32_bf16(af[mi], bfr[ni], acc[mi][ni], 0, 0, 0);
        }
        __syncthreads();
    }

    float* ldsf = (float*)smem;
    #pragma unroll
    for (int mi = 0; mi < 4; ++mi)
        #pragma unroll
        for (int ni = 0; ni < 4; ++ni)
            #pragma unroll
            for (int rr = 0; rr < 4; ++rr) {
                int r = wm + mi * 16 + ((lane >> 4) << 2) + rr;
                int c = wn + ni * 16 + (lane & 15);
                ldsf[r * EPS + c] = acc[mi][ni][rr];
            }
    __syncthreads();

    const int jj = tid & 7;
    #pragma unroll
    for (int pass = 0; pass < 4; ++pass) {
        int r = pass * 32 + (tid >> 3);
        int row = tm + r;
        if (row >= MROWS) continue;
        float s_ = rs_of(ssqIn[row]);
        int b = row / SEQ, q = row - b * SEQ;
        #pragma unroll
        for (int i = 0; i < 4; ++i) {
            int col = tn + i * 32 + jj * 4;
            int part = col >> 9, h = (col >> 6) & 7, d = col & 63;
            float4 v = *(float4*)&ldsf[r * EPS + i * 32 + jj * 4];
            ushort4 s;
            s.x = f2b(v.x * s_); s.y = f2b(v.y * s_); s.z = f2b(v.z * s_); s.w = f2b(v.w * s_);
            *(ushort4*)((u16*)C + (size_t)part * QKVS + (((size_t)(b * 8 + h)) * SEQ + q) * 64 + d) = s;
        }
    }
}

// ---------------- GEMM 128x64, 48KB LDS (3 blocks/CU) ----------------
// MODE 1: fp32 C += delta; bf16 xb mirror; atomicAdd row sumsq -> ssqOut.
// MODE 3: SwiGLU on rs(ssqIn)-scaled pairs -> gp[M][384].
template <int MODE, int K, int NX, int NWG>
__global__ __launch_bounds__(256) void gemm_bt64_k(const u16* __restrict__ A, const u16* __restrict__ B,
                                                   void* __restrict__ C, const float* __restrict__ ssqIn,
                                                   float* __restrict__ ssqOut, u16* __restrict__ xb) {
    __shared__ u16 smem[24576];          // 48KB: A dbuf 2x16KB @0, B dbuf 2x4KB @16384(x2); fp32 [128][68]
    const int tid = threadIdx.x;
    const int lane = tid & 63;
    const int wave = tid >> 6;
    int hw = blockIdx.x;
    constexpr int q8 = NWG >> 3, r8 = NWG & 7;
    int xcd = hw & 7, pos = hw >> 3;
    int work = (xcd < r8 ? xcd * (q8 + 1) : r8 * (q8 + 1) + (xcd - r8) * q8) + pos;
    int ty = work / NX, tx = work - ty * NX;
    const int tm = ty * 128;
    const int tn = tx * 64;
    const int wm = (wave >> 1) * 64;
    const int wn = (wave & 1) * 32;
    f4v acc[4][2] = {};

    constexpr int nk = K >> 6;
#define STAGE64(cur_, kk)                                                               \
    do {                                                                                \
        int k0_ = (kk);                                                                 \
        _Pragma("unroll")                                                               \
        for (int i_ = 0; i_ < 4; ++i_) {                                                \
            int chunk_ = i_ * 256 + tid;                                                \
            int row_ = chunk_ >> 3, kc_ = chunk_ & 7;                                   \
            int gr_ = tm + row_;                                                        \
            gr_ = gr_ < MROWS ? gr_ : MROWS - 1;                                        \
            const u16* srcA_ = A + (size_t)gr_ * K + k0_ + ((kc_ ^ (row_ & 7)) << 3);   \
            __builtin_amdgcn_global_load_lds(                                           \
                (const __attribute__((address_space(1))) void*)srcA_,                   \
                (__attribute__((address_space(3))) void*)(smem + (cur_) * 8192 + (size_t)chunk_ * 8), \
                16, 0, 0);                                                              \
        }                                                                               \
        _Pragma("unroll")                                                               \
        for (int i_ = 0; i_ < 2; ++i_) {                                                \
            int chunk_ = i_ * 256 + tid;                                                \
            int row_ = chunk_ >> 3, kc_ = chunk_ & 7;                                   \
            const u16* srcB_ = B + (size_t)(tn + row_) * K + k0_ + ((kc_ ^ (row_ & 7)) << 3); \
            __builtin_amdgcn_global_load_lds(                                           \
                (const __attribute__((address_space(1))) void*)srcB_,                   \
                (__attribute__((address_space(3))) void*)(smem + 16384 + (cur_) * 4096 + (size_t)chunk_ * 8), \
                16, 0, 0);                                                              \
        }                                                                               \
    } while (0)

    STAGE64(0, 0);
    __syncthreads();
    #pragma unroll
    for (int k = 0; k < nk; ++k) {
        int cur = k & 1;
        if (k + 1 < nk) STAGE64(cur ^ 1, (k + 1) << 6);
        const u16* sa_ = smem + cur * 8192;
        const u16* sb_ = smem + 16384 + cur * 4096;
        #pragma unroll
        for (int ks = 0; ks < 2; ++ks) {
            int kc = ks * 4 + (lane >> 4);
            s8v af[4], bfr[2];
            #pragma unroll
            for (int mi = 0; mi < 4; ++mi) {
                int row = wm + mi * 16 + (lane & 15);
                af[mi] = *(const s8v*)(sa_ + row * 64 + ((kc ^ (row & 7)) << 3));
            }
            #pragma unroll
            for (int ni = 0; ni < 2; ++ni) {
                int row = wn + ni * 16 + (lane & 15);
                bfr[ni] = *(const s8v*)(sb_ + row * 64 + ((kc ^ (row & 7)) << 3));
            }
            #pragma unroll
            for (int mi = 0; mi < 4; ++mi)
                #pragma unroll
                for (int ni = 0; ni < 2; ++ni)
                    acc[mi][ni] = __builtin_amdgcn_mfma_f32_16x16x32_bf16(af[mi], bfr[ni], acc[mi][ni], 0, 0, 0);
        }
        __syncthreads();
    }
#undef STAGE64

    float* ldsf = (float*)smem;
    #pragma unroll
    for (int mi = 0; mi < 4; ++mi)
        #pragma unroll
        for (int ni = 0; ni < 2; ++ni)
            #pragma unroll
            for (int rr = 0; rr < 4; ++rr) {
                int r = wm + mi * 16 + ((lane >> 4) << 2) + rr;
                int c = wn + ni * 16 + (lane & 15);
                ldsf[r * EPS64 + c] = acc[mi][ni][rr];
            }
    __syncthreads();

    const int jj = tid & 7;
    #pragma unroll
    for (int pass = 0; pass < 4; ++pass) {
        int r = pass * 32 + (tid >> 3);
        int row = tm + r;
        if (row >= MROWS) continue;
        if (MODE == 1) {
            float sumsq = 0.f;
            #pragma unroll
            for (int i = 0; i < 2; ++i) {
                float4 v = *(float4*)&ldsf[r * EPS64 + i * 32 + jj * 4];
                int col = tn + i * 32 + jj * 4;
                float* p = (float*)C + (size_t)row * D + col;
                float4 o = *(float4*)p;
                o.x += v.x; o.y += v.y; o.z += v.z; o.w += v.w;
                *(float4*)p = o;
                ushort4 s;
                s.x = f2b(o.x); s.y = f2b(o.y); s.z = f2b(o.z); s.w = f2b(o.w);
                *(ushort4*)(xb + (size_t)row * D + col) = s;
                sumsq += o.x * o.x + o.y * o.y + o.z * o.z + o.w * o.w;
            }
            sumsq += __shfl_xor(sumsq, 1);
            sumsq += __shfl_xor(sumsq, 2);
            sumsq += __shfl_xor(sumsq, 4);
            if (jj == 0) atomicAdd(ssqOut + row, sumsq);
        } else {  // MODE 3: SwiGLU, 64-wide tile = 2 groups of 32 cols ([0..15]=w1, [16..31]=w3)
            float s_ = rs_of(ssqIn[row]);
            #pragma unroll
            for (int i = 0; i < 2; ++i) {
                float a0 = ldsf[r * EPS64 + i * 32 + jj * 2] * s_;
                float a1 = ldsf[r * EPS64 + i * 32 + jj * 2 + 1] * s_;
                float b0 = ldsf[r * EPS64 + i * 32 + 16 + jj * 2] * s_;
                float b1 = ldsf[r * EPS64 + i * 32 + 16 + jj * 2 + 1] * s_;
                float g0 = a0 / (1.f + __expf(-a0)) * b0;
                float g1 = a1 / (1.f + __expf(-a1)) * b1;
                int f = (tn >> 1) + i * 16 + jj * 2;
                unsigned pk = (unsigned)f2b(g0) | ((unsigned)f2b(g1) << 16);
                *(unsigned*)((u16*)C + (size_t)row * FPAD + f) = pk;
            }
        }
    }
}

// ---------------- attention ----------------
__global__ __launch_bounds__(256) void attn_k(const u16* __restrict__ qt, const u16* __restrict__ kt,
                                              const u16* __restrict__ vt, u16* __restrict__ o) {
    const int tid = threadIdx.x;
    if (blockIdx.x >= 64) {
        int sid = blockIdx.x - 64;
        int qtile = sid & 7, bh = sid >> 3;
        int h = bh & 7, b = bh >> 3;
        const size_t slab = (size_t)bh * SEQ * 64;
        const int ql = tid >> 1, half = tid & 1;
        const int q = 1 + qtile * 128 + ql;
        const int q1 = q - 1, r = q1 >> 5, c = q1 & 31;

        const u16* qp = qt + slab + (size_t)q * 64 + half * 32;
        float qf[32];
        #pragma unroll
        for (int cc = 0; cc < 4; ++cc) {
            s8v qv = *(const s8v*)(qp + cc * 8);
            #pragma unroll
            for (int i = 0; i < 8; ++i) qf[cc * 8 + i] = b2f((u16)qv[i]);
        }
        int key[6]; bool valid[6];
        key[0] = 0;      valid[0] = true;
        key[1] = q;      valid[1] = true;
        key[2] = q - 1;  valid[2] = (c > 0);
        key[3] = q + 1;  valid[3] = (c < 31);
        key[4] = q - 32; valid[4] = (r > 0);
        key[5] = q + 32; valid[5] = (r < 31);

        float sc[6];
        #pragma unroll
        for (int j = 0; j < 6; ++j) {
            int kk = valid[j] ? key[j] : 0;
            const u16* kp = kt + slab + (size_t)kk * 64 + half * 32;
            float d = 0.f;
            #pragma unroll
            for (int cc = 0; cc < 4; ++cc) {
                s8v kv = *(const s8v*)(kp + cc * 8);
                #pragma unroll
                for (int i = 0; i < 8; ++i) d += qf[cc * 8 + i] * b2f((u16)kv[i]);
            }
            d += __shfl_xor(d, 1);
            sc[j] = valid[j] ? d * 0.125f : -1e30f;
        }
        float m = sc[0];
        #pragma unroll
        for (int j = 1; j < 6; ++j) m = fmaxf(m, sc[j]);
        float w[6], l = 0.f;
        #pragma unroll
        for (int j = 0; j < 6; ++j) { w[j] = __expf(sc[j] - m); l += w[j]; }
        float inv = 1.f / l;

        float acc[32];
        #pragma unroll
        for (int i = 0; i < 32; ++i) acc[i] = 0.f;
        #pragma unroll
        for (int j = 0; j < 6; ++j) {
            int kk = valid[j] ? key[j] : 0;
            const u16* vp = vt + slab + (size_t)kk * 64 + half * 32;
            #pragma unroll
            for (int cc = 0; cc < 4; ++cc) {
                s8v vv = *(const s8v*)(vp + cc * 8);
                #pragma unroll
                for (int i = 0; i < 8; ++i) acc[cc * 8 + i] += w[j] * b2f((u16)vv[i]);
            }
        }
        u16* orow = o + ((size_t)b * SEQ + q) * D + h * 64 + half * 32;
        #pragma unroll
        for (int cc = 0; cc < 4; ++cc) {
            uint4 pk;
            pk.x = (unsigned)f2b(acc[cc * 8 + 0] * inv) | ((unsigned)f2b(acc[cc * 8 + 1] * inv) << 16);
            pk.y = (unsigned)f2b(acc[cc * 8 + 2] * inv) | ((unsigned)f2b(acc[cc * 8 + 3] * inv) << 16);
            pk.z = (unsigned)f2b(acc[cc * 8 + 4] * inv) | ((unsigned)f2b(acc[cc * 8 + 5] * inv) << 16);
            pk.w = (unsigned)f2b(acc[cc * 8 + 6] * inv) | ((unsigned)f2b(acc[cc * 8 + 7] * inv) << 16);
            *(uint4*)(orow + cc * 8) = pk;
        }
    } else {
        __shared__ float sp[SEQ + 15];
        __shared__ float red[8];
        __shared__ float sacc[4][64];
        int bh = blockIdx.x;
        int h = bh & 7, b = bh >> 3;
        const size_t slab = (size_t)bh * SEQ * 64;
        const int lane = tid & 63, wv = tid >> 6;

        float qf[64];
        #pragma unroll
        for (int cc = 0; cc < 8; ++cc) {
            s8v qv = *(const s8v*)(qt + slab + cc * 8);
            #pragma unroll
            for (int i = 0; i < 8; ++i) qf[cc * 8 + i] = b2f((u16)qv[i]);
        }
        for (int j0 = tid; j0 < SEQ; j0 += 256) {
            const u16* kp = kt + slab + (size_t)j0 * 64;
            float p0 = 0.f, p1 = 0.f, p2 = 0.f, p3 = 0.f;
            #pragma unroll
            for (int cc = 0; cc < 8; ++cc) {
                s8v kv = *(const s8v*)(kp + cc * 8);
                p0 += qf[cc * 8 + 0] * b2f((u16)kv[0]) + qf[cc * 8 + 4] * b2f((u16)kv[4]);
                p1 += qf[cc * 8 + 1] * b2f((u16)kv[1]) + qf[cc * 8 + 5] * b2f((u16)kv[5]);
                p2 += qf[cc * 8 + 2] * b2f((u16)kv[2]) + qf[cc * 8 + 6] * b2f((u16)kv[6]);
                p3 += qf[cc * 8 + 3] * b2f((u16)kv[3]) + qf[cc * 8 + 7] * b2f((u16)kv[7]);
            }
            sp[j0] = ((p0 + p1) + (p2 + p3)) * 0.125f;
        }
        __syncthreads();
        float m = -1e30f;
        for (int j = tid; j < SEQ; j += 256) m = fmaxf(m, sp[j]);
        #pragma unroll
        for (int off = 32; off; off >>= 1) m = fmaxf(m, __shfl_xor(m, off));
        if (lane == 0) red[wv] = m;
        __syncthreads();
        m = fmaxf(fmaxf(red[0], red[1]), fmaxf(red[2], red[3]));
        float lsum = 0.f;
        for (int j = tid; j < SEQ; j += 256) { float e = __expf(sp[j] - m); sp[j] = e; lsum += e; }
        #pragma unroll
        for (int off = 32; off; off >>= 1) lsum += __shfl_xor(lsum, off);
        if (lane == 0) red[4 + wv] = lsum;
        __syncthreads();
        float L = (red[4] + red[5]) + (red[6] + red[7]);
        const int quarter = lane & 3, stripe = lane >> 2;
        float acc[16];
        #pragma unroll
        for (int i = 0; i < 16; ++i) acc[i] = 0.f;
        const int jbase = wv * 256;
        const int njj = (wv == 3) ? 17 : 16;
        for (int jj2 = 0; jj2 < njj; ++jj2) {
            int j = jbase + jj2 * 16 + stripe;
            float wj = (j < SEQ) ? sp[j] : 0.f;
            int je = j < 1024 ? j : 1024;
            const u16* vp = vt + slab + (size_t)je * 64 + quarter * 16;
            s8v v0 = *(const s8v*)(vp);
            s8v v1 = *(const s8v*)(vp + 8);
            #pragma unroll
            for (int i = 0; i < 8; ++i) {
                acc[i]     += wj * b2f((u16)v0[i]);
                acc[8 + i] += wj * b2f((u16)v1[i]);
            }
        }
        #pragma unroll
        for (int off = 4; off <= 32; off <<= 1) {
            #pragma unroll
            for (int i = 0; i < 16; ++i) acc[i] += __shfl_xor(acc[i], off);
        }
        if (lane < 4) {
            #pragma unroll
            for (int i = 0; i < 16; ++i) sacc[wv][lane * 16 + i] = acc[i];
        }
        __syncthreads();
        if (tid < 64) {
            float A = (sacc[0][tid] + sacc[1][tid]) + (sacc[2][tid] + sacc[3][tid]);
            o[((size_t)b * SEQ) * D + h * 64 + tid] = f2b(A / L);
        }
    }
}

extern "C" void kernel_launch(void* const* d_in, const int* in_sizes, int n_in,
                              void* d_out, int out_size, void* d_ws, size_t ws_size,
                              hipStream_t stream) {
    const int M = MROWS;
    const float* x_in = (const float*)d_in[0];
    const float* wqkv = (const float*)d_in[2];
    const float* wo   = (const float*)d_in[3];
    const float* w1   = (const float*)d_in[4];
    const float* w2   = (const float*)d_in[5];
    const float* w3   = (const float*)d_in[6];
    const float* anw  = (const float*)d_in[7];
    const float* fnw  = (const float*)d_in[8];
    float* x = (float*)d_out;

    char* ws = (char*)d_ws;
    auto alloc = [&](size_t n) { char* p = ws; ws += (n + 255) & ~(size_t)255; return p; };
    u16* qkvt  = (u16*)alloc(3 * QKVS * 2);          // Qt|Kt|Vt slabs (gp aliases this)
    u16* xb    = (u16*)alloc((size_t)M * D * 2);     // bf16 mirror of x
    u16* ob    = (u16*)alloc((size_t)M * D * 2);
    float* ssqs = (float*)alloc((size_t)13 * M * 4); // slot 0: init; 1+2l: WO; 2+2l: W2
    u16* wqkvb = (u16*)alloc((size_t)NLAYERS * TD * D * 2);
    u16* wob   = (u16*)alloc((size_t)NLAYERS * D * D * 2);
    u16* w13b  = (u16*)alloc((size_t)NLAYERS * F2I * D * 2);
    u16* w2b   = (u16*)alloc((size_t)NLAYERS * D * FPAD * 2);
    u16* gp = qkvt;   // [M][384], reuses dead qkv slab space

    convAll_k<<<(SEG5 + 255) / 256, 256, 0, stream>>>(wqkv, anw, wo, w1, w3, fnw, w2,
                                                      wqkvb, wob, w13b, w2b, ssqs + M,
                                                      x_in, x, xb, ssqs);

    constexpr int mt = (MROWS + 127) / 128;   // 65
    constexpr int gQKV = mt * (TD / 128);     // 780
    constexpr int gD64 = mt * (D / 64);       // 520
    constexpr int gF64 = mt * (F2I / 64);     // 780
    for (int l = 0; l < NLAYERS; ++l) {
        float* ssqPrev = ssqs + (size_t)(2 * l) * M;       // init (l=0) or W2 of l-1
        float* ssqA    = ssqs + (size_t)(2 * l + 1) * M;   // after WO
        float* ssqB    = ssqs + (size_t)(2 * l + 2) * M;   // after W2
        gemm_qkv_k<512, TD / 128, gQKV><<<gQKV, 256, 0, stream>>>(
            xb, wqkvb + (size_t)l * TD * D, qkvt, ssqPrev);
        attn_k<<<64 + 512, 256, 0, stream>>>(qkvt, qkvt + QKVS, qkvt + 2 * QKVS, ob);
        gemm_bt64_k<1, 512, D / 64, gD64><<<gD64, 256, 0, stream>>>(
            ob, wob + (size_t)l * D * D, x, nullptr, ssqA, xb);
        gemm_bt64_k<3, 512, F2I / 64, gF64><<<gF64, 256, 0, stream>>>(
            xb, w13b + (size_t)l * F2I * D, gp, ssqA, nullptr, nullptr);
        gemm_bt64_k<1, 384, D / 64, gD64><<<gD64, 256, 0, stream>>>(
            gp, w2b + (size_t)l * D * FPAD, x, nullptr, ssqB, xb);
    }
}

// Round 18
// 495.801 us; speedup vs baseline: 1.0475x; 1.0475x over previous
//
#include <hip/hip_runtime.h>

typedef unsigned short u16;
typedef short s8v __attribute__((ext_vector_type(8)));
typedef float f4v __attribute__((ext_vector_type(4)));

#define SEQ 1025
#define BATCH 8
#define MROWS (BATCH * SEQ)   // 8200
#define D 512
#define TD 1536
#define F 352
#define F2I 768               // interleaved+padded w1/w3 rows
#define FPAD 384
#define NLAYERS 6
#define QKVS ((size_t)BATCH * 8 * SEQ * 64)   // elements per Q/K/V transposed slab set
#define EPS 132               // padded fp32 epilogue stride (128-wide tiles)
#define EPS64 68              // padded fp32 epilogue stride (64-wide tiles)

__device__ __forceinline__ u16 f2b(float f) {
    unsigned u;
    __builtin_memcpy(&u, &f, 4);
    unsigned r = u + 0x7fffu + ((u >> 16) & 1u);
    return (u16)(r >> 16);
}
__device__ __forceinline__ float b2f(u16 h) {
    unsigned u = ((unsigned)h) << 16;
    float f;
    __builtin_memcpy(&f, &u, 4);
    return f;
}
__device__ __forceinline__ float rs_of(float ssq) {
    return rsqrtf(ssq * (1.0f / (float)D) + 1e-5f);
}

// ---------------- fused weight conversion + ssq zeroing + init (one launch) ----------------
#define SEG0 (NLAYERS * TD * (D / 4))            // 1179648 (multiple of 256)
#define SEG1 (SEG0 + NLAYERS * D * (D / 4))      // +393216
#define SEG2 (SEG1 + NLAYERS * F2I * (D / 4))    // +589824
#define SEG3 (SEG2 + NLAYERS * D * (FPAD / 4))   // +294912
#define SEG4P (SEG3 + ((12 * MROWS / 4 + 255) & ~255))   // ssq zero, padded to 256
#define SEG5 (SEG4P + MROWS * 128)               // init: 128 threads/row
__global__ __launch_bounds__(256) void convAll_k(const float* __restrict__ wqkv, const float* __restrict__ anw,
                                                 const float* __restrict__ wo,
                                                 const float* __restrict__ w1, const float* __restrict__ w3,
                                                 const float* __restrict__ fnw,
                                                 const float* __restrict__ w2,
                                                 u16* __restrict__ wqkvb, u16* __restrict__ wob,
                                                 u16* __restrict__ w13b, u16* __restrict__ w2b,
                                                 float* __restrict__ ssqz,
                                                 const float* __restrict__ xin, float* __restrict__ x,
                                                 u16* __restrict__ xb, float* __restrict__ ssq0) {
    int i = blockIdx.x * 256 + threadIdx.x;
    if (i < SEG0) {
        int k4 = i & 127;
        int rem = i >> 7;
        int l = rem / TD;
        float4 v = ((const float4*)wqkv)[i];
        float4 w = ((const float4*)(anw + (size_t)l * D))[k4];
        ushort4 r;
        r.x = f2b(v.x * w.x); r.y = f2b(v.y * w.y); r.z = f2b(v.z * w.z); r.w = f2b(v.w * w.w);
        ((ushort4*)wqkvb)[i] = r;
    } else if (i < SEG1) {
        int j = i - SEG0;
        float4 v = ((const float4*)wo)[j];
        ushort4 r;
        r.x = f2b(v.x); r.y = f2b(v.y); r.z = f2b(v.z); r.w = f2b(v.w);
        ((ushort4*)wob)[j] = r;
    } else if (i < SEG2) {
        int j = i - SEG1;
        int k4 = j & 127;
        int rem = j >> 7;                            // l*768 + n
        int n = rem % F2I, l = rem / F2I;
        int k32 = n >> 5, jj = n & 31;
        int f = k32 * 16 + (jj & 15);
        ushort4 r;
        if (f < F) {
            const float* src = (jj < 16) ? (w1 + ((size_t)(l * F + f) * D))
                                         : (w3 + ((size_t)(l * F + f) * D));
            float4 v = ((const float4*)src)[k4];
            float4 w = ((const float4*)(fnw + (size_t)l * D))[k4];
            r.x = f2b(v.x * w.x); r.y = f2b(v.y * w.y); r.z = f2b(v.z * w.z); r.w = f2b(v.w * w.w);
        } else {
            r.x = 0; r.y = 0; r.z = 0; r.w = 0;
        }
        ((ushort4*)w13b)[j] = r;
    } else if (i < SEG3) {
        int j = i - SEG2;
        int k4 = j % (FPAD / 4);
        int rem = j / (FPAD / 4);
        int n = rem % D, l = rem / D;
        ushort4 r;
        if (k4 < F / 4) {
            float4 v = ((const float4*)(w2 + (size_t)(l * D + n) * F))[k4];
            r.x = f2b(v.x); r.y = f2b(v.y); r.z = f2b(v.z); r.w = f2b(v.w);
        } else {
            r.x = 0; r.y = 0; r.z = 0; r.w = 0;
        }
        ((ushort4*)w2b)[j] = r;
    } else if (i < SEG4P) {
        int j = i - SEG3;
        if (j < 12 * MROWS / 4) {
            float4 z = {0.f, 0.f, 0.f, 0.f};
            ((float4*)ssqz)[j] = z;
        }
    } else if (i < SEG5) {
        int j = i - SEG4P;
        int row = j >> 7, t = j & 127;
        int tid = threadIdx.x;
        float4 v = ((const float4*)(xin + (size_t)row * D))[t];
        ((float4*)(x + (size_t)row * D))[t] = v;
        ushort4 pk;
        pk.x = f2b(v.x); pk.y = f2b(v.y); pk.z = f2b(v.z); pk.w = f2b(v.w);
        ((ushort4*)(xb + (size_t)row * D))[t] = pk;
        float ss = v.x * v.x + v.y * v.y + v.z * v.z + v.w * v.w;
        #pragma unroll
        for (int off = 32; off; off >>= 1) ss += __shfl_xor(ss, off);
        __shared__ float red[4];
        if ((tid & 63) == 0) red[tid >> 6] = ss;
        __syncthreads();
        if (tid == 0) ssq0[row] = red[0] + red[1];
        if (tid == 128) ssq0[row] = red[2] + red[3];
    }
}

// ---------------- GEMM 128x128 (MODE 2: QKV scatter; MODE 3: W13 SwiGLU), 64KB dbuf (2/CU) ----------------
#define STAGE_GEMM(bufofs, kk)                                                          \
    do {                                                                                \
        int k0_ = (kk);                                                                 \
        _Pragma("unroll")                                                               \
        for (int i_ = 0; i_ < 4; ++i_) {                                                \
            int chunk_ = i_ * 256 + tid;                                                \
            int row_ = chunk_ >> 3, kc_ = chunk_ & 7;                                   \
            int gr_ = tm + row_;                                                        \
            gr_ = gr_ < MROWS ? gr_ : MROWS - 1;                                        \
            const u16* srcA_ = A + (size_t)gr_ * K + k0_ + ((kc_ ^ (row_ & 7)) << 3);   \
            __builtin_amdgcn_global_load_lds(                                           \
                (const __attribute__((address_space(1))) void*)srcA_,                   \
                (__attribute__((address_space(3))) void*)(smem + (bufofs) + (size_t)chunk_ * 8), \
                16, 0, 0);                                                              \
            const u16* srcB_ = B + (size_t)(tn + row_) * K + k0_ + ((kc_ ^ (row_ & 7)) << 3); \
            __builtin_amdgcn_global_load_lds(                                           \
                (const __attribute__((address_space(1))) void*)srcB_,                   \
                (__attribute__((address_space(3))) void*)(smem + 16384 + (bufofs) + (size_t)chunk_ * 8), \
                16, 0, 0);                                                              \
        }                                                                               \
    } while (0)

template <int MODE, int K, int NX, int NWG>
__global__ __launch_bounds__(256) void gemm128_k(const u16* __restrict__ A, const u16* __restrict__ B,
                                                 void* __restrict__ C, const float* __restrict__ ssqIn) {
    __shared__ u16 smem[34048];
    const int tid = threadIdx.x;
    const int lane = tid & 63;
    const int wave = tid >> 6;
    int hw = blockIdx.x;
    constexpr int q8 = NWG >> 3, r8 = NWG & 7;
    int xcd = hw & 7, pos = hw >> 3;
    int work = (xcd < r8 ? xcd * (q8 + 1) : r8 * (q8 + 1) + (xcd - r8) * q8) + pos;
    int ty = work / NX, tx = work - ty * NX;
    const int tm = ty * 128;
    const int tn = tx * 128;
    const int wm = (wave >> 1) * 64;
    const int wn = (wave & 1) * 64;
    f4v acc[4][4] = {};

    constexpr int nk = K >> 6;
    STAGE_GEMM(0, 0);
    __syncthreads();
    #pragma unroll
    for (int k = 0; k < nk; ++k) {
        int cur = (k & 1) * 8192;
        if (k + 1 < nk) STAGE_GEMM(cur ^ 8192, (k + 1) << 6);
        const u16* sa_ = smem + cur;
        const u16* sb_ = smem + 16384 + cur;
        #pragma unroll
        for (int ks = 0; ks < 2; ++ks) {
            int kc = ks * 4 + (lane >> 4);
            s8v af[4], bfr[4];
            #pragma unroll
            for (int mi = 0; mi < 4; ++mi) {
                int row = wm + mi * 16 + (lane & 15);
                af[mi] = *(const s8v*)(sa_ + row * 64 + ((kc ^ (row & 7)) << 3));
            }
            #pragma unroll
            for (int ni = 0; ni < 4; ++ni) {
                int row = wn + ni * 16 + (lane & 15);
                bfr[ni] = *(const s8v*)(sb_ + row * 64 + ((kc ^ (row & 7)) << 3));
            }
            #pragma unroll
            for (int mi = 0; mi < 4; ++mi)
                #pragma unroll
                for (int ni = 0; ni < 4; ++ni)
                    acc[mi][ni] = __builtin_amdgcn_mfma_f32_16x16x32_bf16(af[mi], bfr[ni], acc[mi][ni], 0, 0, 0);
        }
        __syncthreads();
    }

    float* ldsf = (float*)smem;
    #pragma unroll
    for (int mi = 0; mi < 4; ++mi)
        #pragma unroll
        for (int ni = 0; ni < 4; ++ni)
            #pragma unroll
            for (int rr = 0; rr < 4; ++rr) {
                int r = wm + mi * 16 + ((lane >> 4) << 2) + rr;
                int c = wn + ni * 16 + (lane & 15);
                ldsf[r * EPS + c] = acc[mi][ni][rr];
            }
    __syncthreads();

    const int jj = tid & 7;
    #pragma unroll
    for (int pass = 0; pass < 4; ++pass) {
        int r = pass * 32 + (tid >> 3);
        int row = tm + r;
        if (row >= MROWS) continue;
        float s_ = rs_of(ssqIn[row]);
        if (MODE == 2) {
            int b = row / SEQ, q = row - b * SEQ;
            #pragma unroll
            for (int i = 0; i < 4; ++i) {
                int col = tn + i * 32 + jj * 4;
                int part = col >> 9, h = (col >> 6) & 7, d = col & 63;
                float4 v = *(float4*)&ldsf[r * EPS + i * 32 + jj * 4];
                ushort4 s;
                s.x = f2b(v.x * s_); s.y = f2b(v.y * s_); s.z = f2b(v.z * s_); s.w = f2b(v.w * s_);
                *(ushort4*)((u16*)C + (size_t)part * QKVS + (((size_t)(b * 8 + h)) * SEQ + q) * 64 + d) = s;
            }
        } else {  // MODE 3: SwiGLU, cols [i*32 .. i*32+15]=w1, [i*32+16 .. +31]=w3
            #pragma unroll
            for (int i = 0; i < 4; ++i) {
                float a0 = ldsf[r * EPS + i * 32 + jj * 2] * s_;
                float a1 = ldsf[r * EPS + i * 32 + jj * 2 + 1] * s_;
                float b0 = ldsf[r * EPS + i * 32 + 16 + jj * 2] * s_;
                float b1 = ldsf[r * EPS + i * 32 + 16 + jj * 2 + 1] * s_;
                float g0 = a0 / (1.f + __expf(-a0)) * b0;
                float g1 = a1 / (1.f + __expf(-a1)) * b1;
                int f = (tn >> 1) + i * 16 + jj * 2;
                unsigned pk = (unsigned)f2b(g0) | ((unsigned)f2b(g1) << 16);
                *(unsigned*)((u16*)C + (size_t)row * FPAD + f) = pk;
            }
        }
    }
}

// ---------------- GEMM 128x64 (MODE 1: residual update), 520 blocks, 48KB LDS (3 blocks/CU) ----------------
template <int K, int NX, int NWG>
__global__ __launch_bounds__(256) void gemm_bt64_k(const u16* __restrict__ A, const u16* __restrict__ B,
                                                   float* __restrict__ C,
                                                   float* __restrict__ ssqOut, u16* __restrict__ xb) {
    __shared__ u16 smem[24576];
    const int tid = threadIdx.x;
    const int lane = tid & 63;
    const int wave = tid >> 6;
    int hw = blockIdx.x;
    constexpr int q8 = NWG >> 3, r8 = NWG & 7;
    int xcd = hw & 7, pos = hw >> 3;
    int work = (xcd < r8 ? xcd * (q8 + 1) : r8 * (q8 + 1) + (xcd - r8) * q8) + pos;
    int ty = work / NX, tx = work - ty * NX;
    const int tm = ty * 128;
    const int tn = tx * 64;
    const int wm = (wave >> 1) * 64;
    const int wn = (wave & 1) * 32;
    f4v acc[4][2] = {};

    constexpr int nk = K >> 6;
#define STAGE64(cur_, kk)                                                               \
    do {                                                                                \
        int k0_ = (kk);                                                                 \
        _Pragma("unroll")                                                               \
        for (int i_ = 0; i_ < 4; ++i_) {                                                \
            int chunk_ = i_ * 256 + tid;                                                \
            int row_ = chunk_ >> 3, kc_ = chunk_ & 7;                                   \
            int gr_ = tm + row_;                                                        \
            gr_ = gr_ < MROWS ? gr_ : MROWS - 1;                                        \
            const u16* srcA_ = A + (size_t)gr_ * K + k0_ + ((kc_ ^ (row_ & 7)) << 3);   \
            __builtin_amdgcn_global_load_lds(                                           \
                (const __attribute__((address_space(1))) void*)srcA_,                   \
                (__attribute__((address_space(3))) void*)(smem + (cur_) * 8192 + (size_t)chunk_ * 8), \
                16, 0, 0);                                                              \
        }                                                                               \
        _Pragma("unroll")                                                               \
        for (int i_ = 0; i_ < 2; ++i_) {                                                \
            int chunk_ = i_ * 256 + tid;                                                \
            int row_ = chunk_ >> 3, kc_ = chunk_ & 7;                                   \
            const u16* srcB_ = B + (size_t)(tn + row_) * K + k0_ + ((kc_ ^ (row_ & 7)) << 3); \
            __builtin_amdgcn_global_load_lds(                                           \
                (const __attribute__((address_space(1))) void*)srcB_,                   \
                (__attribute__((address_space(3))) void*)(smem + 16384 + (cur_) * 4096 + (size_t)chunk_ * 8), \
                16, 0, 0);                                                              \
        }                                                                               \
    } while (0)

    STAGE64(0, 0);
    __syncthreads();
    #pragma unroll
    for (int k = 0; k < nk; ++k) {
        int cur = k & 1;
        if (k + 1 < nk) STAGE64(cur ^ 1, (k + 1) << 6);
        const u16* sa_ = smem + cur * 8192;
        const u16* sb_ = smem + 16384 + cur * 4096;
        #pragma unroll
        for (int ks = 0; ks < 2; ++ks) {
            int kc = ks * 4 + (lane >> 4);
            s8v af[4], bfr[2];
            #pragma unroll
            for (int mi = 0; mi < 4; ++mi) {
                int row = wm + mi * 16 + (lane & 15);
                af[mi] = *(const s8v*)(sa_ + row * 64 + ((kc ^ (row & 7)) << 3));
            }
            #pragma unroll
            for (int ni = 0; ni < 2; ++ni) {
                int row = wn + ni * 16 + (lane & 15);
                bfr[ni] = *(const s8v*)(sb_ + row * 64 + ((kc ^ (row & 7)) << 3));
            }
            #pragma unroll
            for (int mi = 0; mi < 4; ++mi)
                #pragma unroll
                for (int ni = 0; ni < 2; ++ni)
                    acc[mi][ni] = __builtin_amdgcn_mfma_f32_16x16x32_bf16(af[mi], bfr[ni], acc[mi][ni], 0, 0, 0);
        }
        __syncthreads();
    }
#undef STAGE64

    float* ldsf = (float*)smem;
    #pragma unroll
    for (int mi = 0; mi < 4; ++mi)
        #pragma unroll
        for (int ni = 0; ni < 2; ++ni)
            #pragma unroll
            for (int rr = 0; rr < 4; ++rr) {
                int r = wm + mi * 16 + ((lane >> 4) << 2) + rr;
                int c = wn + ni * 16 + (lane & 15);
                ldsf[r * EPS64 + c] = acc[mi][ni][rr];
            }
    __syncthreads();

    const int jj = tid & 7;
    #pragma unroll
    for (int pass = 0; pass < 4; ++pass) {
        int r = pass * 32 + (tid >> 3);
        int row = tm + r;
        if (row >= MROWS) continue;
        float sumsq = 0.f;
        #pragma unroll
        for (int i = 0; i < 2; ++i) {
            float4 v = *(float4*)&ldsf[r * EPS64 + i * 32 + jj * 4];
            int col = tn + i * 32 + jj * 4;
            float* p = C + (size_t)row * D + col;
            float4 o = *(float4*)p;
            o.x += v.x; o.y += v.y; o.z += v.z; o.w += v.w;
            *(float4*)p = o;
            ushort4 s;
            s.x = f2b(o.x); s.y = f2b(o.y); s.z = f2b(o.z); s.w = f2b(o.w);
            *(ushort4*)(xb + (size_t)row * D + col) = s;
            sumsq += o.x * o.x + o.y * o.y + o.z * o.z + o.w * o.w;
        }
        sumsq += __shfl_xor(sumsq, 1);
        sumsq += __shfl_xor(sumsq, 2);
        sumsq += __shfl_xor(sumsq, 4);
        if (jj == 0) atomicAdd(ssqOut + row, sumsq);
    }
}

// ---------------- attention ----------------
__global__ __launch_bounds__(256) void attn_k(const u16* __restrict__ qt, const u16* __restrict__ kt,
                                              const u16* __restrict__ vt, u16* __restrict__ o) {
    const int tid = threadIdx.x;
    if (blockIdx.x >= 64) {
        int sid = blockIdx.x - 64;
        int qtile = sid & 7, bh = sid >> 3;
        int h = bh & 7, b = bh >> 3;
        const size_t slab = (size_t)bh * SEQ * 64;
        const int ql = tid >> 1, half = tid & 1;
        const int q = 1 + qtile * 128 + ql;
        const int q1 = q - 1, r = q1 >> 5, c = q1 & 31;

        const u16* qp = qt + slab + (size_t)q * 64 + half * 32;
        float qf[32];
        #pragma unroll
        for (int cc = 0; cc < 4; ++cc) {
            s8v qv = *(const s8v*)(qp + cc * 8);
            #pragma unroll
            for (int i = 0; i < 8; ++i) qf[cc * 8 + i] = b2f((u16)qv[i]);
        }
        int key[6]; bool valid[6];
        key[0] = 0;      valid[0] = true;
        key[1] = q;      valid[1] = true;
        key[2] = q - 1;  valid[2] = (c > 0);
        key[3] = q + 1;  valid[3] = (c < 31);
        key[4] = q - 32; valid[4] = (r > 0);
        key[5] = q + 32; valid[5] = (r < 31);

        float sc[6];
        #pragma unroll
        for (int j = 0; j < 6; ++j) {
            int kk = valid[j] ? key[j] : 0;
            const u16* kp = kt + slab + (size_t)kk * 64 + half * 32;
            float d = 0.f;
            #pragma unroll
            for (int cc = 0; cc < 4; ++cc) {
                s8v kv = *(const s8v*)(kp + cc * 8);
                #pragma unroll
                for (int i = 0; i < 8; ++i) d += qf[cc * 8 + i] * b2f((u16)kv[i]);
            }
            d += __shfl_xor(d, 1);
            sc[j] = valid[j] ? d * 0.125f : -1e30f;
        }
        float m = sc[0];
        #pragma unroll
        for (int j = 1; j < 6; ++j) m = fmaxf(m, sc[j]);
        float w[6], l = 0.f;
        #pragma unroll
        for (int j = 0; j < 6; ++j) { w[j] = __expf(sc[j] - m); l += w[j]; }
        float inv = 1.f / l;

        float acc[32];
        #pragma unroll
        for (int i = 0; i < 32; ++i) acc[i] = 0.f;
        #pragma unroll
        for (int j = 0; j < 6; ++j) {
            int kk = valid[j] ? key[j] : 0;
            const u16* vp = vt + slab + (size_t)kk * 64 + half * 32;
            #pragma unroll
            for (int cc = 0; cc < 4; ++cc) {
                s8v vv = *(const s8v*)(vp + cc * 8);
                #pragma unroll
                for (int i = 0; i < 8; ++i) acc[cc * 8 + i] += w[j] * b2f((u16)vv[i]);
            }
        }
        u16* orow = o + ((size_t)b * SEQ + q) * D + h * 64 + half * 32;
        #pragma unroll
        for (int cc = 0; cc < 4; ++cc) {
            uint4 pk;
            pk.x = (unsigned)f2b(acc[cc * 8 + 0] * inv) | ((unsigned)f2b(acc[cc * 8 + 1] * inv) << 16);
            pk.y = (unsigned)f2b(acc[cc * 8 + 2] * inv) | ((unsigned)f2b(acc[cc * 8 + 3] * inv) << 16);
            pk.z = (unsigned)f2b(acc[cc * 8 + 4] * inv) | ((unsigned)f2b(acc[cc * 8 + 5] * inv) << 16);
            pk.w = (unsigned)f2b(acc[cc * 8 + 6] * inv) | ((unsigned)f2b(acc[cc * 8 + 7] * inv) << 16);
            *(uint4*)(orow + cc * 8) = pk;
        }
    } else {
        __shared__ float sp[SEQ + 15];
        __shared__ float red[8];
        __shared__ float sacc[4][64];
        int bh = blockIdx.x;
        int h = bh & 7, b = bh >> 3;
        const size_t slab = (size_t)bh * SEQ * 64;
        const int lane = tid & 63, wv = tid >> 6;

        float qf[64];
        #pragma unroll
        for (int cc = 0; cc < 8; ++cc) {
            s8v qv = *(const s8v*)(qt + slab + cc * 8);
            #pragma unroll
            for (int i = 0; i < 8; ++i) qf[cc * 8 + i] = b2f((u16)qv[i]);
        }
        for (int j0 = tid; j0 < SEQ; j0 += 256) {
            const u16* kp = kt + slab + (size_t)j0 * 64;
            float p0 = 0.f, p1 = 0.f, p2 = 0.f, p3 = 0.f;
            #pragma unroll
            for (int cc = 0; cc < 8; ++cc) {
                s8v kv = *(const s8v*)(kp + cc * 8);
                p0 += qf[cc * 8 + 0] * b2f((u16)kv[0]) + qf[cc * 8 + 4] * b2f((u16)kv[4]);
                p1 += qf[cc * 8 + 1] * b2f((u16)kv[1]) + qf[cc * 8 + 5] * b2f((u16)kv[5]);
                p2 += qf[cc * 8 + 2] * b2f((u16)kv[2]) + qf[cc * 8 + 6] * b2f((u16)kv[6]);
                p3 += qf[cc * 8 + 3] * b2f((u16)kv[3]) + qf[cc * 8 + 7] * b2f((u16)kv[7]);
            }
            sp[j0] = ((p0 + p1) + (p2 + p3)) * 0.125f;
        }
        __syncthreads();
        float m = -1e30f;
        for (int j = tid; j < SEQ; j += 256) m = fmaxf(m, sp[j]);
        #pragma unroll
        for (int off = 32; off; off >>= 1) m = fmaxf(m, __shfl_xor(m, off));
        if (lane == 0) red[wv] = m;
        __syncthreads();
        m = fmaxf(fmaxf(red[0], red[1]), fmaxf(red[2], red[3]));
        float lsum = 0.f;
        for (int j = tid; j < SEQ; j += 256) { float e = __expf(sp[j] - m); sp[j] = e; lsum += e; }
        #pragma unroll
        for (int off = 32; off; off >>= 1) lsum += __shfl_xor(lsum, off);
        if (lane == 0) red[4 + wv] = lsum;
        __syncthreads();
        float L = (red[4] + red[5]) + (red[6] + red[7]);
        const int quarter = lane & 3, stripe = lane >> 2;
        float acc[16];
        #pragma unroll
        for (int i = 0; i < 16; ++i) acc[i] = 0.f;
        const int jbase = wv * 256;
        const int njj = (wv == 3) ? 17 : 16;
        for (int jj2 = 0; jj2 < njj; ++jj2) {
            int j = jbase + jj2 * 16 + stripe;
            float wj = (j < SEQ) ? sp[j] : 0.f;
            int je = j < 1024 ? j : 1024;
            const u16* vp = vt + slab + (size_t)je * 64 + quarter * 16;
            s8v v0 = *(const s8v*)(vp);
            s8v v1 = *(const s8v*)(vp + 8);
            #pragma unroll
            for (int i = 0; i < 8; ++i) {
                acc[i]     += wj * b2f((u16)v0[i]);
                acc[8 + i] += wj * b2f((u16)v1[i]);
            }
        }
        #pragma unroll
        for (int off = 4; off <= 32; off <<= 1) {
            #pragma unroll
            for (int i = 0; i < 16; ++i) acc[i] += __shfl_xor(acc[i], off);
        }
        if (lane < 4) {
            #pragma unroll
            for (int i = 0; i < 16; ++i) sacc[wv][lane * 16 + i] = acc[i];
        }
        __syncthreads();
        if (tid < 64) {
            float A = (sacc[0][tid] + sacc[1][tid]) + (sacc[2][tid] + sacc[3][tid]);
            o[((size_t)b * SEQ) * D + h * 64 + tid] = f2b(A / L);
        }
    }
}

extern "C" void kernel_launch(void* const* d_in, const int* in_sizes, int n_in,
                              void* d_out, int out_size, void* d_ws, size_t ws_size,
                              hipStream_t stream) {
    const int M = MROWS;
    const float* x_in = (const float*)d_in[0];
    const float* wqkv = (const float*)d_in[2];
    const float* wo   = (const float*)d_in[3];
    const float* w1   = (const float*)d_in[4];
    const float* w2   = (const float*)d_in[5];
    const float* w3   = (const float*)d_in[6];
    const float* anw  = (const float*)d_in[7];
    const float* fnw  = (const float*)d_in[8];
    float* x = (float*)d_out;

    char* ws = (char*)d_ws;
    auto alloc = [&](size_t n) { char* p = ws; ws += (n + 255) & ~(size_t)255; return p; };
    u16* qkvt  = (u16*)alloc(3 * QKVS * 2);          // Qt|Kt|Vt slabs (gp aliases this)
    u16* xb    = (u16*)alloc((size_t)M * D * 2);     // bf16 mirror of x
    u16* ob    = (u16*)alloc((size_t)M * D * 2);
    float* ssqs = (float*)alloc((size_t)13 * M * 4); // slot 0: init; 1+2l: WO; 2+2l: W2
    u16* wqkvb = (u16*)alloc((size_t)NLAYERS * TD * D * 2);
    u16* wob   = (u16*)alloc((size_t)NLAYERS * D * D * 2);
    u16* w13b  = (u16*)alloc((size_t)NLAYERS * F2I * D * 2);
    u16* w2b   = (u16*)alloc((size_t)NLAYERS * D * FPAD * 2);
    u16* gp = qkvt;   // [M][384], reuses dead qkv slab space

    convAll_k<<<(SEG5 + 255) / 256, 256, 0, stream>>>(wqkv, anw, wo, w1, w3, fnw, w2,
                                                      wqkvb, wob, w13b, w2b, ssqs + M,
                                                      x_in, x, xb, ssqs);

    constexpr int mt = (MROWS + 127) / 128;   // 65
    constexpr int gQKV = mt * (TD / 128);     // 780
    constexpr int gD64 = mt * (D / 64);       // 520
    constexpr int gF   = mt * (F2I / 128);    // 390
    for (int l = 0; l < NLAYERS; ++l) {
        float* ssqPrev = ssqs + (size_t)(2 * l) * M;       // init (l=0) or W2 of l-1
        float* ssqA    = ssqs + (size_t)(2 * l + 1) * M;   // after WO
        float* ssqB    = ssqs + (size_t)(2 * l + 2) * M;   // after W2
        gemm128_k<2, 512, TD / 128, gQKV><<<gQKV, 256, 0, stream>>>(
            xb, wqkvb + (size_t)l * TD * D, qkvt, ssqPrev);
        attn_k<<<64 + 512, 256, 0, stream>>>(qkvt, qkvt + QKVS, qkvt + 2 * QKVS, ob);
        gemm_bt64_k<512, D / 64, gD64><<<gD64, 256, 0, stream>>>(
            ob, wob + (size_t)l * D * D, x, ssqA, xb);
        gemm128_k<3, 512, F2I / 128, gF><<<gF, 256, 0, stream>>>(
            xb, w13b + (size_t)l * F2I * D, gp, ssqA);
        gemm_bt64_k<384, D / 64, gD64><<<gD64, 256, 0, stream>>>(
            gp, w2b + (size_t)l * D * FPAD, x, ssqB, xb);
    }
}